// Round 1
// baseline (1559.269 us; speedup 1.0000x reference)
//
#include <hip/hip_runtime.h>

typedef unsigned short u16;
typedef __bf16 bf16x8 __attribute__((ext_vector_type(8)));
typedef float f32x4 __attribute__((ext_vector_type(4)));
typedef unsigned int u32x4 __attribute__((ext_vector_type(4)));

#define BB 16
#define CC 768
#define PP 2048
#define FF 3072

__device__ __forceinline__ float b2f(u16 u) {
  unsigned int x = ((unsigned int)u) << 16;
  return __builtin_bit_cast(float, x);
}
__device__ __forceinline__ u16 f2b(float f) {
  unsigned int x = __builtin_bit_cast(unsigned int, f);
  x += 0x7fffu + ((x >> 16) & 1u);
  return (u16)(x >> 16);
}
__device__ __forceinline__ float gelu_f(float x) {
  return 0.5f * x * (1.0f + erff(x * 0.7071067811865475f));
}

typedef __attribute__((address_space(1))) const unsigned int g_u32;
typedef __attribute__((address_space(3))) unsigned int l_u32;
__device__ __forceinline__ void gl_lds16(const u16* g, u16* l) {
  __builtin_amdgcn_global_load_lds((g_u32*)g, (l_u32*)l, 16, 0, 0);
}

// ---------------- weight prep: Wt[n,k] = g[k]*W[k,n], bf16 ----------------
__global__ void wtr_k(const float* __restrict__ W, const float* __restrict__ g,
                      u16* __restrict__ Wt, int K, int N) {
  __shared__ float t[64][65];
  int n0 = blockIdx.x * 64, k0 = blockIdx.y * 64;
  int tx = threadIdx.x & 63, ty = threadIdx.x >> 6;
  for (int i = 0; i < 16; ++i) {
    int k = k0 + ty + i * 4;
    float sc = g ? g[k] : 1.0f;
    t[ty + i * 4][tx] = W[(long)k * N + n0 + tx] * sc;
  }
  __syncthreads();
  for (int i = 0; i < 16; ++i) {
    int n = n0 + ty + i * 4;
    Wt[(long)n * K + k0 + tx] = f2b(t[tx][ty + i * 4]);
  }
}

// b'[n] = b[n] + sum_k nb[k]*W[k,n]
__global__ void bfuse_k(const float* __restrict__ b, const float* __restrict__ nb,
                        const float* __restrict__ W, float* __restrict__ outb,
                        int K, int N) {
  __shared__ float red[4][64];
  int n = blockIdx.x * 64 + (threadIdx.x & 63);
  int slice = threadIdx.x >> 6;
  float acc = 0.f;
#pragma unroll 4
  for (int k = slice; k < K; k += 4) acc += nb[k] * W[(long)k * N + n];
  red[slice][threadIdx.x & 63] = acc;
  __syncthreads();
  if (slice == 0)
    outb[n] = b[n] + red[0][threadIdx.x & 63] + red[1][threadIdx.x & 63] +
              red[2][threadIdx.x & 63] + red[3][threadIdx.x & 63];
}

// ---------------- x stats over C (x is [B,C,P]) ----------------
__global__ void x_stats_k(const float* __restrict__ x, float* __restrict__ mean,
                          float* __restrict__ rstd) {
  int i = blockIdx.x * 256 + threadIdx.x;  // over B*P
  int b = i >> 11, p = i & 2047;
  const float* xp = x + (long)b * CC * PP + p;
  float s = 0.f, sq = 0.f;
  for (int c = 0; c < CC; ++c) { float f = xp[(long)c * PP]; s += f; sq += f * f; }
  float m = s * (1.0f / 768.0f);
  float var = sq * (1.0f / 768.0f) - m * m;
  mean[i] = m;
  rstd[i] = rsqrtf(var + 1e-5f);
}

// xhat[b,p,c] = (x[b,c,p]-m)*rstd  (tiled transpose, bf16 out)
__global__ void xhat_tr_k(const float* __restrict__ x, const float* __restrict__ mean,
                          const float* __restrict__ rstd, u16* __restrict__ xh) {
  __shared__ float t[64][65];
  int p0 = blockIdx.x * 64, c0 = blockIdx.y * 64, b = blockIdx.z;
  int tx = threadIdx.x & 63, ty = threadIdx.x >> 6;
  const float* xb = x + (long)b * CC * PP;
  for (int i = 0; i < 16; ++i) {
    int c = c0 + ty + i * 4;
    t[ty + i * 4][tx] = xb[(long)c * PP + p0 + tx];
  }
  __syncthreads();
  u16* ob = xh + (long)b * PP * CC;
  for (int i = 0; i < 16; ++i) {
    int p = p0 + ty + i * 4;
    int ridx = (b << 11) + p;
    float mn = mean[ridx], rs = rstd[ridx];
    ob[(long)p * CC + c0 + tx] = f2b((t[tx][ty + i * 4] - mn) * rs);
  }
}

// out[b,c,p] = x[b,c,p] + dec_out[b,p,c]
__global__ void final_tr_k(const u16* __restrict__ dout, const float* __restrict__ x,
                           float* __restrict__ outp) {
  __shared__ float t[64][65];
  int p0 = blockIdx.x * 64, c0 = blockIdx.y * 64, b = blockIdx.z;
  int tx = threadIdx.x & 63, ty = threadIdx.x >> 6;
  const u16* db = dout + (long)b * PP * CC;
  for (int i = 0; i < 16; ++i) {
    int p = p0 + ty + i * 4;
    t[ty + i * 4][tx] = b2f(db[(long)p * CC + c0 + tx]);
  }
  __syncthreads();
  const float* xb = x + (long)b * CC * PP;
  float* ob = outp + (long)b * CC * PP;
  for (int i = 0; i < 16; ++i) {
    int c = c0 + ty + i * 4;
    long off = (long)c * PP + p0 + tx;
    ob[off] = xb[off] + t[tx][ty + i * 4];
  }
}

// ---------------- SimpleReasoning gate ----------------
__global__ void parts_sr_k(const float* __restrict__ parts,
                           const float* __restrict__ w1, const float* __restrict__ b1,
                           const float* __restrict__ w2, const float* __restrict__ b2,
                           float* __restrict__ parts1) {
  int b = blockIdx.x, t = threadIdx.x;
  __shared__ float g[64], g1[64], gate[64];
  int r = t >> 2, l4 = t & 3;
  const float* pr = parts + ((long)b * 64 + r) * CC;
  float m = -1e30f;
  for (int c = l4; c < CC; c += 4) m = fmaxf(m, pr[c]);
  m = fmaxf(m, __shfl_xor(m, 1));
  m = fmaxf(m, __shfl_xor(m, 2));
  if (l4 == 0) g[r] = m;
  __syncthreads();
  if (t < 64) {
    float a = b1[t];
    for (int k = 0; k < 64; ++k) a += g[k] * w1[k * 64 + t];
    g1[t] = gelu_f(a);
  }
  __syncthreads();
  if (t < 64) {
    float a = b2[t];
    for (int k = 0; k < 64; ++k) a += g1[k] * w2[k * 64 + t];
    gate[t] = 1.0f / (1.0f + expf(-a));
  }
  __syncthreads();
  const float* pb = parts + (long)b * 64 * CC;
  float* ob = parts1 + (long)b * 64 * CC;
  for (int i = t; i < 64 * CC; i += 256) {
    int rr = i / CC;
    ob[i] = pb[i] * (1.0f + gate[rr]);
  }
}

// ---------------- LN rows (C=768), wave per row, bf16 out (no affine) --------
template <typename T>
__global__ void ln_rows_k(const T* __restrict__ in, u16* __restrict__ outp, int rows) {
  int row = blockIdx.x * 4 + (threadIdx.x >> 6);
  if (row >= rows) return;
  int lane = threadIdx.x & 63;
  const T* ip = in + (long)row * CC;
  float v[12];
  float s = 0.f, sq = 0.f;
  for (int i = 0; i < 12; ++i) {
    float f;
    if constexpr (sizeof(T) == 2) f = b2f(((const u16*)ip)[lane + i * 64]);
    else f = ((const float*)ip)[lane + i * 64];
    v[i] = f; s += f; sq += f * f;
  }
  for (int o = 32; o; o >>= 1) { s += __shfl_xor(s, o); sq += __shfl_xor(sq, o); }
  float mean = s * (1.0f / 768.0f);
  float var = sq * (1.0f / 768.0f) - mean * mean;
  float rstd = rsqrtf(var + 1e-5f);
  u16* op = outp + (long)row * CC;
  for (int i = 0; i < 12; ++i) op[lane + i * 64] = f2b((v[i] - mean) * rstd);
}

// ---------------- softmaxes ----------------
__global__ void softmax_enc_k(const float* __restrict__ attn, u16* __restrict__ sm,
                              float* __restrict__ attn0) {
  int row = blockIdx.x * 4 + (threadIdx.x >> 6);  // B*64 rows, len 2048
  int lane = threadIdx.x & 63;
  const float* ap = attn + (long)row * PP;
  float v[32];
  float m = -1e30f;
  for (int i = 0; i < 32; ++i) { v[i] = ap[lane + i * 64]; m = fmaxf(m, v[i]); }
  for (int o = 32; o; o >>= 1) m = fmaxf(m, __shfl_xor(m, o));
  float s = 0.f;
  for (int i = 0; i < 32; ++i) { float e = expf(v[i] - m); v[i] = e; s += e; }
  for (int o = 32; o; o >>= 1) s += __shfl_xor(s, o);
  float inv = 1.0f / s;
  u16* sp = sm + (long)row * PP;
  for (int i = 0; i < 32; ++i) sp[lane + i * 64] = f2b(v[i] * inv);
  if (lane == 0) attn0[row] = m;  // m = max(relu*scale) >= 0 == attn_0
}

__global__ void softmax_dec_k(const float* __restrict__ attn, u16* __restrict__ sm) {
  long row = (long)blockIdx.x * 4 + (threadIdx.x >> 6);  // B*P rows, len 64
  int lane = threadIdx.x & 63;
  float v = attn[row * 64 + lane];
  float m = v;
  for (int o = 32; o; o >>= 1) m = fmaxf(m, __shfl_xor(m, o));
  float e = expf(v - m);
  float s = e;
  for (int o = 32; o; o >>= 1) s += __shfl_xor(s, o);
  sm[row * 64 + lane] = f2b(e / s);
}

// ---------- FAST GEMM (m97 structure): C = A[M,K]*B[N,K]^T, M,N%128==0, K%32==0
// Kept for the small (M=1024) ops.
// EPI: 0 bias->bf16 | 1 bias+gelu->bf16 | 3 bias+(xhat/rstd+mean) res->bf16
//      4 bias+res32->f32
template <int EPI>
__global__ __launch_bounds__(256) void gemmf_k(
    const u16* __restrict__ A, const u16* __restrict__ Bm, void* __restrict__ Cm,
    const float* __restrict__ bias, int M, int N, int K,
    const u16* __restrict__ rxh, const float* __restrict__ rmean,
    const float* __restrict__ rrstd, long rro, const float* __restrict__ res32) {
  __shared__ __align__(16) u16 As[128 * 32];
  __shared__ __align__(16) u16 Bs[128 * 32];
  const int nbx = N >> 7;
  const int nwg = gridDim.x;
  int tile = blockIdx.x;
  if ((nwg & 7) == 0) {  // XCD-contiguous row-panel chunks (bijective: nwg%8==0)
    tile = (tile & 7) * (nwg >> 3) + (tile >> 3);
  }
  const int bm0 = (tile / nbx) << 7;
  const int bn0 = (tile % nbx) << 7;
  const int tid = threadIdx.x;
  const int lane = tid & 63;
  const int wave = tid >> 6;
  const int laneq = lane & 15, lanek = lane >> 4;
  const int wm = (wave >> 1) << 6, wn = (wave & 1) << 6;
  const int srow = wave * 32 + (lane >> 2);
  const int scol = (lane & 3) << 3;
  const u16* Ag0 = A + (long)(bm0 + srow) * K + scol;
  const u16* Ag1 = A + (long)(bm0 + srow + 16) * K + scol;
  const u16* Bg0 = Bm + (long)(bn0 + srow) * K + scol;
  const u16* Bg1 = Bm + (long)(bn0 + srow + 16) * K + scol;
  u16* lA0 = As + wave * 1024;
  u16* lA1 = As + wave * 1024 + 512;
  u16* lB0 = Bs + wave * 1024;
  u16* lB1 = Bs + wave * 1024 + 512;
  f32x4 acc[4][4] = {};
  for (int k0 = 0; k0 < K; k0 += 32) {
    gl_lds16(Ag0 + k0, lA0);
    gl_lds16(Ag1 + k0, lA1);
    gl_lds16(Bg0 + k0, lB0);
    gl_lds16(Bg1 + k0, lB1);
    __syncthreads();  // compiler drains vmcnt before barrier
    bf16x8 af[4], bfr[4];
#pragma unroll
    for (int i = 0; i < 4; ++i)
      af[i] = *(const bf16x8*)(As + (wm + i * 16 + laneq) * 32 + (lanek << 3));
#pragma unroll
    for (int i = 0; i < 4; ++i)
      bfr[i] = *(const bf16x8*)(Bs + (wn + i * 16 + laneq) * 32 + (lanek << 3));
#pragma unroll
    for (int mi = 0; mi < 4; ++mi)
#pragma unroll
      for (int ni = 0; ni < 4; ++ni)
        acc[mi][ni] =
            __builtin_amdgcn_mfma_f32_16x16x32_bf16(af[mi], bfr[ni], acc[mi][ni], 0, 0, 0);
    __syncthreads();  // protect LDS before next-iter staging
  }
#pragma unroll
  for (int mi = 0; mi < 4; ++mi) {
#pragma unroll
    for (int r = 0; r < 4; ++r) {
      const int row = bm0 + wm + mi * 16 + (lanek << 2) + r;
      float mn = 0.f, istd = 0.f;
      if constexpr (EPI == 3) {
        long gr = rro + row;
        mn = rmean[gr];
        istd = 1.0f / rrstd[gr];
      }
#pragma unroll
      for (int ni = 0; ni < 4; ++ni) {
        const int col = bn0 + wn + ni * 16 + laneq;
        float v = acc[mi][ni][r] + bias[col];
        long off = (long)row * N + col;
        if constexpr (EPI == 0) {
          ((u16*)Cm)[off] = f2b(v);
        } else if constexpr (EPI == 1) {
          ((u16*)Cm)[off] = f2b(gelu_f(v));
        } else if constexpr (EPI == 3) {
          v += b2f(rxh[(rro + row) * 768 + col]) * istd + mn;
          ((u16*)Cm)[off] = f2b(v);
        } else {
          ((float*)Cm)[off] = v + res32[off];
        }
      }
    }
  }
}

// ---------- 256x256 deep-pipeline GEMM (T3+T4+T5): C = A[M,K]*B[N,K]^T
// M,N%256==0, K%32==0, K>=96. 512 threads = 8 waves (2M x 4N), per-wave 128x64.
// 4-deep LDS ring (4 x (A 256x32 + B 256x32) = 128 KiB), counted s_waitcnt
// vmcnt(8) (never 0 in main loop), ONE raw s_barrier per K-step, staging for
// tile t+3 issued before compute of tile t. XOR swizzle slot^=(row&3) applied
// via pre-swizzled global source (global_load_lds dest stays linear).
// EPI: 0 bias->bf16 | 1 bias+gelu->bf16 | 3 bias+(xhat/rstd+mean) res->bf16
template <int EPI>
__global__ __launch_bounds__(512, 2) void gemm256_k(
    const u16* __restrict__ A, const u16* __restrict__ Bm, void* __restrict__ Cm,
    const float* __restrict__ bias, int M, int N, int K,
    const u16* __restrict__ rxh, const float* __restrict__ rmean,
    const float* __restrict__ rrstd, long rro) {
  __shared__ __align__(16) u16 As[4 * 8192];
  __shared__ __align__(16) u16 Bs[4 * 8192];
  const int nbx = N >> 8;
  const int nwg = gridDim.x;
  int tile = blockIdx.x;
  if ((nwg & 7) == 0) {
    tile = (tile & 7) * (nwg >> 3) + (tile >> 3);
  }
  const int bm0 = (tile / nbx) << 8;
  const int bn0 = (tile % nbx) << 8;
  const int tid = threadIdx.x;
  const int lane = tid & 63;
  const int wave = tid >> 6;
  const int laneq = lane & 15, lanek = lane >> 4;
  const int wrow = (wave >> 2) << 7;  // 0 / 128
  const int wcol = (wave & 3) << 6;   // 0 / 64 / 128 / 192
  // ---- staging geometry: wave w covers rows [w*32, w*32+32) of both tiles,
  // 2 calls of 16 rows each; lane l -> row base+ (l>>2), 16B slot (l&3).
  // Pre-swizzled source chunk = (l&3) ^ (row&3) so LDS slot ^= (row&3).
  const int srow = lane >> 2;                                // 0..15
  const int schunk = ((lane & 3) ^ (srow & 3)) << 3;         // element offset in K
  const u16* pA0 = A + (long)(bm0 + wave * 32 + srow) * K + schunk;
  const u16* pA1 = A + (long)(bm0 + wave * 32 + 16 + srow) * K + schunk;
  const u16* pB0 = Bm + (long)(bn0 + wave * 32 + srow) * K + schunk;
  const u16* pB1 = Bm + (long)(bn0 + wave * 32 + 16 + srow) * K + schunk;
  const int lds0 = wave * 1024;        // elements: (wave*32 rows)*32
  const int lds1 = wave * 1024 + 512;  // +16 rows
  // ---- read geometry (swizzled): slot = lanek ^ (row&3), row&3 == laneq&3
  const int aoff = (wrow + laneq) * 32 + ((lanek ^ (laneq & 3)) << 3);
  const int boff = (wcol + laneq) * 32 + ((lanek ^ (laneq & 3)) << 3);
  f32x4 acc[8][4] = {};
  const int NT = K >> 5;

  auto stage = [&](int ts) {
    const long ko = (long)ts * 32;
    u16* dA = As + (ts & 3) * 8192;
    u16* dB = Bs + (ts & 3) * 8192;
    gl_lds16(pA0 + ko, dA + lds0);
    gl_lds16(pA1 + ko, dA + lds1);
    gl_lds16(pB0 + ko, dB + lds0);
    gl_lds16(pB1 + ko, dB + lds1);
  };
  auto compute = [&](int t) {
    const u16* Ab = As + (t & 3) * 8192;
    const u16* Bb = Bs + (t & 3) * 8192;
    bf16x8 af[8], bfr[4];
#pragma unroll
    for (int i = 0; i < 8; ++i) af[i] = *(const bf16x8*)(Ab + aoff + i * 512);
#pragma unroll
    for (int i = 0; i < 4; ++i) bfr[i] = *(const bf16x8*)(Bb + boff + i * 512);
    __builtin_amdgcn_s_setprio(1);
#pragma unroll
    for (int mi = 0; mi < 8; ++mi)
#pragma unroll
      for (int ni = 0; ni < 4; ++ni)
        acc[mi][ni] =
            __builtin_amdgcn_mfma_f32_16x16x32_bf16(af[mi], bfr[ni], acc[mi][ni], 0, 0, 0);
    __builtin_amdgcn_s_setprio(0);
  };

  // prologue: 3 tiles in flight
  stage(0);
  stage(1);
  stage(2);
  int t = 0;
  for (; t < NT - 2; ++t) {
    // tile t's 4 calls are the oldest; <=12 outstanding -> vmcnt(8) confirms them.
    asm volatile("s_waitcnt vmcnt(8)" ::: "memory");
    asm volatile("s_barrier" ::: "memory");
    if (t + 3 < NT) stage(t + 3);  // into buf[(t+3)&3] == old tile t-1 (done)
    compute(t);
  }
  asm volatile("s_waitcnt vmcnt(4)" ::: "memory");
  asm volatile("s_barrier" ::: "memory");
  compute(t);
  ++t;
  asm volatile("s_waitcnt vmcnt(0)" ::: "memory");
  asm volatile("s_barrier" ::: "memory");
  compute(t);

#pragma unroll
  for (int mi = 0; mi < 8; ++mi) {
#pragma unroll
    for (int r = 0; r < 4; ++r) {
      const int row = bm0 + wrow + mi * 16 + (lanek << 2) + r;
      float mn = 0.f, istd = 0.f;
      if constexpr (EPI == 3) {
        long gr = rro + row;
        mn = rmean[gr];
        istd = 1.0f / rrstd[gr];
      }
#pragma unroll
      for (int ni = 0; ni < 4; ++ni) {
        const int col = bn0 + wcol + ni * 16 + laneq;
        float v = acc[mi][ni][r] + bias[col];
        long off = (long)row * N + col;
        if constexpr (EPI == 0) {
          ((u16*)Cm)[off] = f2b(v);
        } else if constexpr (EPI == 1) {
          ((u16*)Cm)[off] = f2b(gelu_f(v));
        } else {
          v += b2f(rxh[(rro + row) * 768 + col]) * istd + mn;
          ((u16*)Cm)[off] = f2b(v);
        }
      }
    }
  }
}

// ---------------- GEMM (general/batched path, attention ops) ----------------
// BNT=true : B is [N,K] row-major (NT). BNT=false: B is [K,N] row-major (NN).
// EPI: 0 bias->bf16 | 2 relu*scale->f32
template <int EPI, bool BNT>
__global__ __launch_bounds__(256) void gemm_k(
    const u16* __restrict__ A, const u16* __restrict__ Bm, void* __restrict__ Cm,
    const float* __restrict__ bias, int M, int N, int K,
    long sA, long sB, long sC, float scale) {
  __shared__ __align__(16) u16 As[128][40];
  __shared__ __align__(16) u16 Bs[128][40];
  const int bn0 = blockIdx.x * 128, bm0 = blockIdx.y * 128;
  const int bz = blockIdx.z;
  const u16* Ab = A + (long)bz * sA;
  const u16* Bb = Bm + (long)bz * sB;
  const int tid = threadIdx.x;
  const int lane = tid & 63;
  const int wave = tid >> 6;
  const int wm = (wave >> 1) << 6;
  const int wn = (wave & 1) << 6;
  const int laneq = lane & 15, lanek = lane >> 4;
  f32x4 acc[4][4] = {};
  for (int k0 = 0; k0 < K; k0 += 32) {
    __syncthreads();
#pragma unroll
    for (int j = 0; j < 2; ++j) {
      int v = tid + j * 256;
      int m = v >> 2, kc = (v & 3) << 3;
      u32x4 val = {0, 0, 0, 0};
      if (bm0 + m < M) val = *(const u32x4*)(Ab + (long)(bm0 + m) * K + k0 + kc);
      *(u32x4*)(&As[m][kc]) = val;
    }
    if constexpr (BNT) {
#pragma unroll
      for (int j = 0; j < 2; ++j) {
        int v = tid + j * 256;
        int n = v >> 2, kc = (v & 3) << 3;
        u32x4 val = {0, 0, 0, 0};
        if (bn0 + n < N) val = *(const u32x4*)(Bb + (long)(bn0 + n) * K + k0 + kc);
        *(u32x4*)(&Bs[n][kc]) = val;
      }
    } else {
#pragma unroll
      for (int j = 0; j < 2; ++j) {
        int v = tid + j * 256;
        int kk = v >> 4, nc = (v & 15) << 3;
        u32x4 val = {0, 0, 0, 0};
        if (bn0 + nc < N) val = *(const u32x4*)(Bb + (long)(k0 + kk) * N + bn0 + nc);
        union { u32x4 v4; u16 u[8]; } uu;
        uu.v4 = val;
#pragma unroll
        for (int e = 0; e < 8; ++e) Bs[nc + e][kk] = uu.u[e];
      }
    }
    __syncthreads();
    bf16x8 af[4], bfr[4];
#pragma unroll
    for (int i = 0; i < 4; ++i)
      af[i] = *(const bf16x8*)(&As[wm + i * 16 + laneq][lanek << 3]);
#pragma unroll
    for (int i = 0; i < 4; ++i)
      bfr[i] = *(const bf16x8*)(&Bs[wn + i * 16 + laneq][lanek << 3]);
#pragma unroll
    for (int mi = 0; mi < 4; ++mi)
#pragma unroll
      for (int ni = 0; ni < 4; ++ni)
        acc[mi][ni] =
            __builtin_amdgcn_mfma_f32_16x16x32_bf16(af[mi], bfr[ni], acc[mi][ni], 0, 0, 0);
  }
#pragma unroll
  for (int mi = 0; mi < 4; ++mi) {
#pragma unroll
    for (int ni = 0; ni < 4; ++ni) {
      int col = bn0 + wn + ni * 16 + laneq;
      if (col >= N) continue;
#pragma unroll
      for (int r = 0; r < 4; ++r) {
        int row = bm0 + wm + mi * 16 + (lanek << 2) + r;
        if (row >= M) continue;
        float v = acc[mi][ni][r];
        long off = (long)bz * sC + (long)row * N + col;
        if constexpr (EPI == 0) {
          if (bias) v += bias[col];
          ((u16*)Cm)[off] = f2b(v);
        } else {
          ((float*)Cm)[off] = fmaxf(v, 0.0f) * scale;
        }
      }
    }
  }
}

extern "C" void kernel_launch(void* const* d_in, const int* in_sizes, int n_in,
                              void* d_out, int out_size, void* d_ws, size_t ws_size,
                              hipStream_t stream) {
  (void)in_sizes; (void)n_in; (void)out_size;
  const float* x        = (const float*)d_in[0];
  const float* parts    = (const float*)d_in[1];
  const float* enc_nq_g = (const float*)d_in[2];
  const float* enc_nq_b = (const float*)d_in[3];
  const float* enc_nk_g = (const float*)d_in[4];
  const float* enc_nk_b = (const float*)d_in[5];
  const float* enc_nv_g = (const float*)d_in[6];
  const float* enc_nv_b = (const float*)d_in[7];
  const float* enc_wq   = (const float*)d_in[8];
  const float* enc_wk   = (const float*)d_in[9];
  const float* enc_wv   = (const float*)d_in[10];
  const float* enc_wp   = (const float*)d_in[11];
  const float* enc_bq   = (const float*)d_in[12];
  const float* enc_bk   = (const float*)d_in[13];
  const float* enc_bv   = (const float*)d_in[14];
  const float* enc_bp   = (const float*)d_in[15];
  const float* dec_nq_g = (const float*)d_in[16];
  const float* dec_nq_b = (const float*)d_in[17];
  const float* dec_nk_g = (const float*)d_in[18];
  const float* dec_nk_b = (const float*)d_in[19];
  const float* dec_nv_g = (const float*)d_in[20];
  const float* dec_nv_b = (const float*)d_in[21];
  const float* dec_wq   = (const float*)d_in[22];
  const float* dec_wk   = (const float*)d_in[23];
  const float* dec_wv   = (const float*)d_in[24];
  const float* dec_wp   = (const float*)d_in[25];
  const float* dec_bq   = (const float*)d_in[26];
  const float* dec_bk   = (const float*)d_in[27];
  const float* dec_bv   = (const float*)d_in[28];
  const float* dec_bp   = (const float*)d_in[29];
  const float* ffn_ng   = (const float*)d_in[30];
  const float* ffn_nb   = (const float*)d_in[31];
  const float* ffn_w1   = (const float*)d_in[32];
  const float* ffn_b1   = (const float*)d_in[33];
  const float* ffn_w2   = (const float*)d_in[34];
  const float* ffn_b2   = (const float*)d_in[35];
  const float* sr_w1    = (const float*)d_in[36];
  const float* sr_b1    = (const float*)d_in[37];
  const float* sr_w2    = (const float*)d_in[38];
  const float* sr_b2    = (const float*)d_in[39];
  float* outp = (float*)d_out;

  char* base = (char*)d_ws;
  size_t used = 0;
  auto alloc = [&](size_t bytes) -> void* {
    void* p = base + used;
    used += (bytes + 255) & ~(size_t)255;
    return p;
  };
  const long MC = (long)CC * CC;
  u16* WqeT = (u16*)alloc(MC * 2);
  u16* WkeT = (u16*)alloc(MC * 2);
  u16* WveT = (u16*)alloc(MC * 2);
  u16* WpeT = (u16*)alloc(MC * 2);
  u16* WqdT = (u16*)alloc(MC * 2);
  u16* WkdT = (u16*)alloc(MC * 2);
  u16* WvdT = (u16*)alloc(MC * 2);
  u16* WpdT = (u16*)alloc(MC * 2);
  u16* W1T  = (u16*)alloc((long)CC * FF * 2);
  u16* W2T  = (u16*)alloc((long)CC * FF * 2);
  float* bqe = (float*)alloc(CC * 4);
  float* bke = (float*)alloc(CC * 4);
  float* bve = (float*)alloc(CC * 4);
  float* bqd = (float*)alloc(CC * 4);
  float* bkd = (float*)alloc(CC * 4);
  float* bvd = (float*)alloc(CC * 4);
  float* b1f = (float*)alloc(FF * 4);
  float* meanx = (float*)alloc((long)BB * PP * 4);
  float* rstdx = (float*)alloc((long)BB * PP * 4);
  const long BPC = (long)BB * PP * CC;          // 25.2M elems
  u16* bufA = (u16*)alloc(BPC * 2);             // xhat -> dec_out
  u16* bufB = (u16*)alloc(BPC * 2);             // kn -> feats1/f1hat -> pv_dec
  u16* bufC = (u16*)alloc(BPC * 2);             // vn -> qn_dec
  const long PC = (long)BB * 64 * CC;           // 786432
  float* parts1   = (float*)alloc(PC * 4);
  u16*   p1hat    = (u16*)alloc(PC * 2);
  u16*   qn_e     = (u16*)alloc(PC * 2);
  float* attn_e   = (float*)alloc((long)BB * 64 * PP * 4);
  u16*   sm_e     = (u16*)alloc((long)BB * 64 * PP * 2);
  u16*   pv_e     = (u16*)alloc(PC * 2);
  float* parts_in = (float*)alloc(PC * 4);
  u16*   pin_hat  = (u16*)alloc(PC * 2);
  u16*   kn_d     = (u16*)alloc(PC * 2);
  u16*   vn_d     = (u16*)alloc(PC * 2);
  float* attn_d   = (float*)alloc((long)BB * PP * 64 * 4);
  u16*   sm_d     = (u16*)alloc((long)BB * PP * 64 * 2);
  // ff1 last: pick the largest FFN chunking that fits the remaining workspace.
  int chunk_rows = 32768;
  while (chunk_rows > 4096 &&
         used + (size_t)chunk_rows * FF * 2 > ws_size)
    chunk_rows >>= 1;
  u16* ff1 = (u16*)alloc((long)chunk_rows * FF * 2);
  if (used > ws_size) return;  // loud failure (validation will catch)

  const float scale = 0.03608439182435161f;  // 768^-0.5
  dim3 blk(256);
  dim3 blk2(512);

  // 1) weight prep
  wtr_k<<<dim3(12, 12), blk, 0, stream>>>(enc_wq, enc_nq_g, WqeT, CC, CC);
  wtr_k<<<dim3(12, 12), blk, 0, stream>>>(enc_wk, enc_nk_g, WkeT, CC, CC);
  wtr_k<<<dim3(12, 12), blk, 0, stream>>>(enc_wv, enc_nv_g, WveT, CC, CC);
  wtr_k<<<dim3(12, 12), blk, 0, stream>>>(enc_wp, nullptr,  WpeT, CC, CC);
  wtr_k<<<dim3(12, 12), blk, 0, stream>>>(dec_wq, dec_nq_g, WqdT, CC, CC);
  wtr_k<<<dim3(12, 12), blk, 0, stream>>>(dec_wk, dec_nk_g, WkdT, CC, CC);
  wtr_k<<<dim3(12, 12), blk, 0, stream>>>(dec_wv, dec_nv_g, WvdT, CC, CC);
  wtr_k<<<dim3(12, 12), blk, 0, stream>>>(dec_wp, nullptr,  WpdT, CC, CC);
  wtr_k<<<dim3(48, 12), blk, 0, stream>>>(ffn_w1, ffn_ng, W1T, CC, FF);
  wtr_k<<<dim3(12, 48), blk, 0, stream>>>(ffn_w2, nullptr, W2T, FF, CC);
  bfuse_k<<<12, blk, 0, stream>>>(enc_bq, enc_nq_b, enc_wq, bqe, CC, CC);
  bfuse_k<<<12, blk, 0, stream>>>(enc_bk, enc_nk_b, enc_wk, bke, CC, CC);
  bfuse_k<<<12, blk, 0, stream>>>(enc_bv, enc_nv_b, enc_wv, bve, CC, CC);
  bfuse_k<<<12, blk, 0, stream>>>(dec_bq, dec_nq_b, dec_wq, bqd, CC, CC);
  bfuse_k<<<12, blk, 0, stream>>>(dec_bk, dec_nk_b, dec_wk, bkd, CC, CC);
  bfuse_k<<<12, blk, 0, stream>>>(dec_bv, dec_nv_b, dec_wv, bvd, CC, CC);
  bfuse_k<<<48, blk, 0, stream>>>(ffn_b1, ffn_nb, ffn_w1, b1f, CC, FF);

  // 2) x LN stats + xhat transpose
  x_stats_k<<<128, blk, 0, stream>>>(x, meanx, rstdx);
  xhat_tr_k<<<dim3(32, 12, 16), blk, 0, stream>>>(x, meanx, rstdx, bufA);

  // 3) SimpleReasoning + LN(parts1)
  parts_sr_k<<<16, blk, 0, stream>>>(parts, sr_w1, sr_b1, sr_w2, sr_b2, parts1);
  ln_rows_k<float><<<256, blk, 0, stream>>>(parts1, p1hat, 1024);

  // 4) enc projections (q on small path; K/V on 256^2 deep pipeline)
  gemmf_k<0><<<48, blk, 0, stream>>>(p1hat, WqeT, qn_e, bqe, 1024, CC, CC,
      nullptr, nullptr, nullptr, 0, nullptr);
  gemm256_k<0><<<384, blk2, 0, stream>>>(bufA, WkeT, bufB, bke, 32768, CC, CC,
      nullptr, nullptr, nullptr, 0);
  gemm256_k<0><<<384, blk2, 0, stream>>>(bufA, WveT, bufC, bve, 32768, CC, CC,
      nullptr, nullptr, nullptr, 0);

  // 5) enc attention: attn = relu(qn@kn^T)*scale, softmax(+attn_0), PV, proj+res
  gemm_k<2, true><<<dim3(16, 1, 16), blk, 0, stream>>>(qn_e, bufB, attn_e, nullptr,
      64, PP, CC, (long)64 * CC, (long)PP * CC, (long)64 * PP, scale);
  softmax_enc_k<<<256, blk, 0, stream>>>(attn_e, sm_e, outp + (long)BB * CC * PP);
  gemm_k<0, false><<<dim3(6, 1, 16), blk, 0, stream>>>(sm_e, bufC, pv_e, nullptr,
      64, CC, PP, (long)64 * PP, (long)PP * CC, (long)64 * CC, 0.f);
  gemmf_k<4><<<48, blk, 0, stream>>>(pv_e, WpeT, parts_in, enc_bp, 1024, CC, CC,
      nullptr, nullptr, nullptr, 0, parts1);

  // 6) dec K/V from LN(parts_in)
  ln_rows_k<float><<<256, blk, 0, stream>>>(parts_in, pin_hat, 1024);
  gemmf_k<0><<<48, blk, 0, stream>>>(pin_hat, WkdT, kn_d, bkd, 1024, CC, CC,
      nullptr, nullptr, nullptr, 0, nullptr);
  gemmf_k<0><<<48, blk, 0, stream>>>(pin_hat, WvdT, vn_d, bvd, 1024, CC, CC,
      nullptr, nullptr, nullptr, 0, nullptr);

  // 7) FFN: feats1 = x + gelu(xhat@W1'+b1')@W2 + b2  -> bufB
  for (long r0 = 0; r0 < 32768; r0 += chunk_rows) {
    gemm256_k<1><<<(chunk_rows / 256) * 12, blk2, 0, stream>>>(
        bufA + r0 * CC, W1T, ff1, b1f, chunk_rows, FF, CC,
        nullptr, nullptr, nullptr, 0);
    gemm256_k<3><<<(chunk_rows / 256) * 3, blk2, 0, stream>>>(
        ff1, W2T, bufB + r0 * CC, ffn_b2, chunk_rows, CC, FF,
        bufA, meanx, rstdx, r0);
  }
  // 8) LN(feats1) in place, dec q projection -> bufC
  ln_rows_k<u16><<<8192, blk, 0, stream>>>(bufB, bufB, 32768);
  gemm256_k<0><<<384, blk2, 0, stream>>>(bufB, WqdT, bufC, bqd, 32768, CC, CC,
      nullptr, nullptr, nullptr, 0);

  // 9) dec attention
  gemm_k<2, true><<<dim3(1, 16, 16), blk, 0, stream>>>(bufC, kn_d, attn_d, nullptr,
      PP, 64, CC, (long)PP * CC, (long)64 * CC, (long)PP * 64, scale);
  softmax_dec_k<<<8192, blk, 0, stream>>>(attn_d, sm_d);
  gemm_k<0, false><<<dim3(6, 16, 16), blk, 0, stream>>>(sm_d, vn_d, bufB, nullptr,
      PP, CC, 64, (long)PP * 64, (long)64 * CC, (long)PP * CC, 0.f);
  gemm256_k<0><<<384, blk2, 0, stream>>>(bufB, WpdT, bufA, dec_bp, 32768, CC, CC,
      nullptr, nullptr, nullptr, 0);

  // 10) final: out[b,c,p] = x + dec_out^T
  final_tr_k<<<dim3(32, 12, 16), blk, 0, stream>>>(bufA, x, outp);
}